// Round 7
// baseline (159.346 us; speedup 1.0000x reference)
//
#include <hip/hip_runtime.h>

// HybridLoss: 0.8*MSE + 0.2*(1-SSIM), SSIM via separable 11x11 Gaussian (sigma=1.5)
// Input: pred, target f32 (32,3,512,512). Output: scalar f32.
// Streaming strip (64 wide x 256 tall), 512-thread blocks, 32-row chunks through
// a 42-row circular LDS buffer of ONE float4/px: (mu_x, mu_y, E[x^2+y^2], E[xy]).
// sigma_x2+sigma_y2 = E[x^2+y^2] - mu_x^2 - mu_y^2 recovers the SSIM denominator.
// launch_bounds(512,6): VGPR cap 85 >> natural 64 (round-5: capping below natural
// allocation spilled xa/ya to scratch, 80 MB writes). 3 blocks/CU (43.7 KB LDS).

#define W 512
#define H 512
#define NIMG 96
#define TX 64
#define CHUNK 32
#define STRIP 256
#define NITER 8            // STRIP/CHUNK
#define BUF 42             // circular rows: CHUNK + 10-row window overlap
#define PAD4 65            // float4 row stride: 1040 B == 16 mod 128 -> uniform banks
#define NSLOT 128

__global__ void hybrid_init(double* __restrict__ ws) {
    int t = threadIdx.x;
    if (t < 2 * NSLOT) ws[t] = 0.0;
}

__global__ __launch_bounds__(512, 6) void hybrid_main(
    const float* __restrict__ pred, const float* __restrict__ targ,
    double* __restrict__ ws)
{
    __shared__ float4 s_q[BUF][PAD4];   // 42*1040 = 43680 B -> 3 blocks/CU

    const int tid = threadIdx.x;
    const float* __restrict__ pp = pred + (size_t)blockIdx.z * (H * W);
    const float* __restrict__ tp = targ + (size_t)blockIdx.z * (H * W);
    const int xbase = blockIdx.x * TX;
    const int Y0 = blockIdx.y * STRIP;

    // Normalized 1D Gaussian (separable form of outer(g,g)/sum), f32 like ref
    float gw[11];
    {
        float s = 0.f;
#pragma unroll
        for (int k = 0; k < 11; ++k) {
            float d = (float)(k - 5);
            gw[k] = expf(-d * d / 4.5f);   // 2*sigma^2 = 4.5
            s += gw[k];
        }
        float inv = 1.f / s;
#pragma unroll
        for (int k = 0; k < 11; ++k) gw[k] *= inv;
    }

    const int hrow_i = tid >> 4;       // 0..31 : hconv row-in-chunk
    const int g      = tid & 15;       // 4-col group
    const int c0     = g * 4;
    const int A0     = xbase + c0 - 8; // aligned 20-px window [A0, A0+20)
    const bool inX   = (A0 >= 0) && (A0 + 20 <= W);

    const int wv = tid >> 6;           // wave 0..7 (vconv 4-row runs)
    const int cc = tid & 63;           // output column within tile

    float mse_local = 0.f, ssim_local = 0.f;

    // hconv one image row (gy) into circular slot; MSE on raw pred if owned.
    auto hconv_row = [&](int gy, int slot, bool own) {
        float xa[20], ya[20];
        if (gy >= 0 && gy < H) {
            const float* __restrict__ px = pp + (size_t)gy * W;
            const float* __restrict__ py = tp + (size_t)gy * W;
            if (inX) {
                const float4* qx = (const float4*)(px + A0);
                const float4* qy = (const float4*)(py + A0);
#pragma unroll
                for (int v = 0; v < 5; ++v) {
                    float4 a = qx[v], b = qy[v];
                    xa[4*v+0]=a.x; xa[4*v+1]=a.y; xa[4*v+2]=a.z; xa[4*v+3]=a.w;
                    ya[4*v+0]=b.x; ya[4*v+1]=b.y; ya[4*v+2]=b.z; ya[4*v+3]=b.w;
                }
            } else {
#pragma unroll
                for (int j = 0; j < 20; ++j) {
                    int col = A0 + j;
                    bool ok = (col >= 0) && (col < W);
                    xa[j] = ok ? px[col] : 0.f;
                    ya[j] = ok ? py[col] : 0.f;
                }
            }
        } else {
#pragma unroll
            for (int j = 0; j < 20; ++j) { xa[j] = 0.f; ya[j] = 0.f; }
        }

        float a0[4]={0,0,0,0}, a1[4]={0,0,0,0}, a2[4]={0,0,0,0}, a3[4]={0,0,0,0};
#pragma unroll
        for (int j = 0; j < 14; ++j) {        // window positions 3..16
            float xv = xa[3 + j], yv = ya[3 + j];
            if (j >= 5 && j <= 8 && own) {    // owned pixels, raw pred
                float d = xv - yv;
                mse_local = fmaf(d, d, mse_local);
            }
            float cx = fminf(fmaxf(xv, 0.f), 1.f);   // SSIM uses clipped pred
            float s2 = fmaf(yv, yv, cx * cx);        // x^2 + y^2
            float xy = cx * yv;
#pragma unroll
            for (int i = 0; i < 4; ++i) {
                int k = j - i;
                if (k >= 0 && k < 11) {
                    float w = gw[k];
                    a0[i] = fmaf(w, cx, a0[i]);
                    a1[i] = fmaf(w, yv, a1[i]);
                    a2[i] = fmaf(w, s2, a2[i]);
                    a3[i] = fmaf(w, xy, a3[i]);
                }
            }
        }
#pragma unroll
        for (int i = 0; i < 4; ++i)
            s_q[slot][c0 + i] = make_float4(a0[i], a1[i], a2[i], a3[i]);
    };

    // Prologue: ext rows 0..9 (gy = Y0-5 .. Y0+4) -> slots 0..9
    if (hrow_i < 10) {
        hconv_row(Y0 - 5 + hrow_i, hrow_i, hrow_i >= 5);
    }

    const float C1 = 1e-4f, C2 = 9e-4f;
    int hb = 10;   // slot of ext row 32k+10 (first hconv row of iter k)
    int vb = 0;    // slot of ext row 32k   (window base of iter k)

    for (int k = 0; k < NITER; ++k) {
        // ---- hconv-write: ext rows 32k+10 .. 32k+41 (1 task/thread) ----
        {
            int ext  = CHUNK * k + 10 + hrow_i;
            int slot = hb + hrow_i; if (slot >= BUF) slot -= BUF;
            hconv_row(Y0 - 5 + ext, slot, ext <= STRIP + 4);
        }
        __syncthreads();

        // ---- vconv: output rows 32k + 4*wv .. +3 (1 task/thread) ----
        {
            int t0 = vb + 4 * wv; if (t0 >= BUF) t0 -= BUF;
            float ax[4]={0,0,0,0}, ay[4]={0,0,0,0};
            float as[4]={0,0,0,0}, axy[4]={0,0,0,0};
#pragma unroll
            for (int j = 0; j < 14; ++j) {
                int s = t0 + j; if (s >= BUF) s -= BUF;
                float4 q = s_q[s][cc];
#pragma unroll
                for (int i = 0; i < 4; ++i) {
                    int kk = j - i;
                    if (kk >= 0 && kk < 11) {
                        float w = gw[kk];
                        ax [i] = fmaf(w, q.x, ax [i]);
                        ay [i] = fmaf(w, q.y, ay [i]);
                        as [i] = fmaf(w, q.z, as [i]);
                        axy[i] = fmaf(w, q.w, axy[i]);
                    }
                }
            }
#pragma unroll
            for (int i = 0; i < 4; ++i) {
                float mu_x2 = ax[i]*ax[i], mu_y2 = ay[i]*ay[i], mu_xy = ax[i]*ay[i];
                float ssum = as[i] - mu_x2 - mu_y2;      // sigma_x2 + sigma_y2
                float sxy  = axy[i] - mu_xy;
                float num = (2.f*mu_xy + C1) * (2.f*sxy + C2);
                float den = (mu_x2 + mu_y2 + C1) * (ssum + C2);
                ssim_local = fmaf(num, __builtin_amdgcn_rcpf(den), ssim_local);
            }
        }
        __syncthreads();

        hb += CHUNK; if (hb >= BUF) hb -= BUF;
        vb += CHUNK; if (vb >= BUF) vb -= BUF;
    }

    // ---- Per-wave reduction + spread f64 atomics ----
    float m = mse_local, s2 = ssim_local;
#pragma unroll
    for (int off = 32; off; off >>= 1) {
        m  += __shfl_down(m, off);
        s2 += __shfl_down(s2, off);
    }
    if ((tid & 63) == 0) {
        int flat = blockIdx.x + 8 * (blockIdx.y + 2 * blockIdx.z);
        int slot = (flat * 8 + wv) & (NSLOT - 1);
        atomicAdd(&ws[slot], (double)m);
        atomicAdd(&ws[NSLOT + slot], (double)s2);
    }
}

__global__ void hybrid_fin(const double* __restrict__ ws, float* __restrict__ out) {
    int t = threadIdx.x;  // 64 threads
    double m = ws[t] + ws[t + 64];
    double s = ws[NSLOT + t] + ws[NSLOT + t + 64];
#pragma unroll
    for (int off = 32; off; off >>= 1) {
        m += __shfl_down(m, off);
        s += __shfl_down(s, off);
    }
    if (t == 0) {
        const double N = (double)NIMG * H * W;
        double mse  = m / N;
        double ssim = s / N;
        out[0] = (float)(0.8 * mse + 0.2 * (1.0 - ssim));
    }
}

extern "C" void kernel_launch(void* const* d_in, const int* in_sizes, int n_in,
                              void* d_out, int out_size, void* d_ws, size_t ws_size,
                              hipStream_t stream) {
    const float* pred = (const float*)d_in[0];
    const float* targ = (const float*)d_in[1];
    double* ws = (double*)d_ws;
    float* out = (float*)d_out;

    hybrid_init<<<1, 256, 0, stream>>>(ws);
    dim3 grid(W / TX, H / STRIP, NIMG);
    hybrid_main<<<grid, dim3(512), 0, stream>>>(pred, targ, ws);
    hybrid_fin<<<1, 64, 0, stream>>>(ws, out);
}

// Round 8
// 142.040 us; speedup vs baseline: 1.1218x; 1.1218x over previous
//
#include <hip/hip_runtime.h>

// HybridLoss: 0.8*MSE + 0.2*(1-SSIM), SSIM via separable 11x11 Gaussian (sigma=1.5)
// Input: pred, target f32 (32,3,512,512). Output: scalar f32.
// Streaming strip (64 wide x 256 tall), 512-thread blocks, 32-row chunks through
// a 42-row circular LDS buffer of ONE float4/px: (mu_x, mu_y, E[x^2+y^2], E[xy]).
// sigma_x2+sigma_y2 = E[x^2+y^2] - mu_x^2 - mu_y^2 recovers the SSIM denominator.
//
// __launch_bounds__ 2nd arg MUST stay <=4: min-waves=6 made hipcc clamp VGPR to 40
// and spill xa/ya to scratch (r5: 80 MB, r7: 59 MB scratch writes, VALUBusy -20pts).
// With (512,4) the compiler's natural ~64 VGPR fits; HW residency is set by actual
// resources (3 blocks/CU: 3x44 KB LDS <= 160 KB, 64 VGPR -> 8 waves/SIMD).

#define W 512
#define H 512
#define NIMG 96
#define TX 64
#define CHUNK 32
#define STRIP 256
#define NITER 8            // STRIP/CHUNK
#define BUF 42             // circular rows: CHUNK + 10-row window overlap
#define PAD4 65            // float4 row stride: 1040 B == 16 mod 128 -> uniform banks
#define NSLOT 128

__global__ void hybrid_init(double* __restrict__ ws) {
    int t = threadIdx.x;
    if (t < 2 * NSLOT) ws[t] = 0.0;
}

__global__ __launch_bounds__(512, 4) void hybrid_main(
    const float* __restrict__ pred, const float* __restrict__ targ,
    double* __restrict__ ws)
{
    __shared__ float4 s_q[BUF][PAD4];   // 42*1040 = 43680 B -> 3 blocks/CU

    const int tid = threadIdx.x;
    const float* __restrict__ pp = pred + (size_t)blockIdx.z * (H * W);
    const float* __restrict__ tp = targ + (size_t)blockIdx.z * (H * W);
    const int xbase = blockIdx.x * TX;
    const int Y0 = blockIdx.y * STRIP;

    // Normalized 1D Gaussian (separable form of outer(g,g)/sum), f32 like ref
    float gw[11];
    {
        float s = 0.f;
#pragma unroll
        for (int k = 0; k < 11; ++k) {
            float d = (float)(k - 5);
            gw[k] = expf(-d * d / 4.5f);   // 2*sigma^2 = 4.5
            s += gw[k];
        }
        float inv = 1.f / s;
#pragma unroll
        for (int k = 0; k < 11; ++k) gw[k] *= inv;
    }

    const int hrow_i = tid >> 4;       // 0..31 : hconv row-in-chunk
    const int g      = tid & 15;       // 4-col group
    const int c0     = g * 4;
    const int A0     = xbase + c0 - 8; // aligned 20-px window [A0, A0+20)
    const bool inX   = (A0 >= 0) && (A0 + 20 <= W);

    const int wv = tid >> 6;           // wave 0..7 (vconv 4-row runs)
    const int cc = tid & 63;           // output column within tile

    float mse_local = 0.f, ssim_local = 0.f;

    // hconv one image row (gy) into circular slot; MSE on raw pred if owned.
    auto hconv_row = [&](int gy, int slot, bool own) {
        float xa[20], ya[20];
        if (gy >= 0 && gy < H) {
            const float* __restrict__ px = pp + (size_t)gy * W;
            const float* __restrict__ py = tp + (size_t)gy * W;
            if (inX) {
                const float4* qx = (const float4*)(px + A0);
                const float4* qy = (const float4*)(py + A0);
#pragma unroll
                for (int v = 0; v < 5; ++v) {
                    float4 a = qx[v], b = qy[v];
                    xa[4*v+0]=a.x; xa[4*v+1]=a.y; xa[4*v+2]=a.z; xa[4*v+3]=a.w;
                    ya[4*v+0]=b.x; ya[4*v+1]=b.y; ya[4*v+2]=b.z; ya[4*v+3]=b.w;
                }
            } else {
#pragma unroll
                for (int j = 0; j < 20; ++j) {
                    int col = A0 + j;
                    bool ok = (col >= 0) && (col < W);
                    xa[j] = ok ? px[col] : 0.f;
                    ya[j] = ok ? py[col] : 0.f;
                }
            }
        } else {
#pragma unroll
            for (int j = 0; j < 20; ++j) { xa[j] = 0.f; ya[j] = 0.f; }
        }

        float a0[4]={0,0,0,0}, a1[4]={0,0,0,0}, a2[4]={0,0,0,0}, a3[4]={0,0,0,0};
#pragma unroll
        for (int j = 0; j < 14; ++j) {        // window positions 3..16
            float xv = xa[3 + j], yv = ya[3 + j];
            if (j >= 5 && j <= 8 && own) {    // owned pixels, raw pred
                float d = xv - yv;
                mse_local = fmaf(d, d, mse_local);
            }
            float cx = fminf(fmaxf(xv, 0.f), 1.f);   // SSIM uses clipped pred
            float s2 = fmaf(yv, yv, cx * cx);        // x^2 + y^2
            float xy = cx * yv;
#pragma unroll
            for (int i = 0; i < 4; ++i) {
                int k = j - i;
                if (k >= 0 && k < 11) {
                    float w = gw[k];
                    a0[i] = fmaf(w, cx, a0[i]);
                    a1[i] = fmaf(w, yv, a1[i]);
                    a2[i] = fmaf(w, s2, a2[i]);
                    a3[i] = fmaf(w, xy, a3[i]);
                }
            }
        }
#pragma unroll
        for (int i = 0; i < 4; ++i)
            s_q[slot][c0 + i] = make_float4(a0[i], a1[i], a2[i], a3[i]);
    };

    // Prologue: ext rows 0..9 (gy = Y0-5 .. Y0+4) -> slots 0..9
    if (hrow_i < 10) {
        hconv_row(Y0 - 5 + hrow_i, hrow_i, hrow_i >= 5);
    }

    const float C1 = 1e-4f, C2 = 9e-4f;
    int hb = 10;   // slot of ext row 32k+10 (first hconv row of iter k)
    int vb = 0;    // slot of ext row 32k   (window base of iter k)

    for (int k = 0; k < NITER; ++k) {
        // ---- hconv-write: ext rows 32k+10 .. 32k+41 (1 task/thread) ----
        {
            int ext  = CHUNK * k + 10 + hrow_i;
            int slot = hb + hrow_i; if (slot >= BUF) slot -= BUF;
            hconv_row(Y0 - 5 + ext, slot, ext <= STRIP + 4);
        }
        __syncthreads();

        // ---- vconv: output rows 32k + 4*wv .. +3 (1 task/thread) ----
        {
            int t0 = vb + 4 * wv; if (t0 >= BUF) t0 -= BUF;
            float ax[4]={0,0,0,0}, ay[4]={0,0,0,0};
            float as[4]={0,0,0,0}, axy[4]={0,0,0,0};
#pragma unroll
            for (int j = 0; j < 14; ++j) {
                int s = t0 + j; if (s >= BUF) s -= BUF;
                float4 q = s_q[s][cc];
#pragma unroll
                for (int i = 0; i < 4; ++i) {
                    int kk = j - i;
                    if (kk >= 0 && kk < 11) {
                        float w = gw[kk];
                        ax [i] = fmaf(w, q.x, ax [i]);
                        ay [i] = fmaf(w, q.y, ay [i]);
                        as [i] = fmaf(w, q.z, as [i]);
                        axy[i] = fmaf(w, q.w, axy[i]);
                    }
                }
            }
#pragma unroll
            for (int i = 0; i < 4; ++i) {
                float mu_x2 = ax[i]*ax[i], mu_y2 = ay[i]*ay[i], mu_xy = ax[i]*ay[i];
                float ssum = as[i] - mu_x2 - mu_y2;      // sigma_x2 + sigma_y2
                float sxy  = axy[i] - mu_xy;
                float num = (2.f*mu_xy + C1) * (2.f*sxy + C2);
                float den = (mu_x2 + mu_y2 + C1) * (ssum + C2);
                ssim_local = fmaf(num, __builtin_amdgcn_rcpf(den), ssim_local);
            }
        }
        __syncthreads();

        hb += CHUNK; if (hb >= BUF) hb -= BUF;
        vb += CHUNK; if (vb >= BUF) vb -= BUF;
    }

    // ---- Per-wave reduction + spread f64 atomics ----
    float m = mse_local, s2 = ssim_local;
#pragma unroll
    for (int off = 32; off; off >>= 1) {
        m  += __shfl_down(m, off);
        s2 += __shfl_down(s2, off);
    }
    if ((tid & 63) == 0) {
        int flat = blockIdx.x + 8 * (blockIdx.y + 2 * blockIdx.z);
        int slot = (flat * 8 + wv) & (NSLOT - 1);
        atomicAdd(&ws[slot], (double)m);
        atomicAdd(&ws[NSLOT + slot], (double)s2);
    }
}

__global__ void hybrid_fin(const double* __restrict__ ws, float* __restrict__ out) {
    int t = threadIdx.x;  // 64 threads
    double m = ws[t] + ws[t + 64];
    double s = ws[NSLOT + t] + ws[NSLOT + t + 64];
#pragma unroll
    for (int off = 32; off; off >>= 1) {
        m += __shfl_down(m, off);
        s += __shfl_down(s, off);
    }
    if (t == 0) {
        const double N = (double)NIMG * H * W;
        double mse  = m / N;
        double ssim = s / N;
        out[0] = (float)(0.8 * mse + 0.2 * (1.0 - ssim));
    }
}

extern "C" void kernel_launch(void* const* d_in, const int* in_sizes, int n_in,
                              void* d_out, int out_size, void* d_ws, size_t ws_size,
                              hipStream_t stream) {
    const float* pred = (const float*)d_in[0];
    const float* targ = (const float*)d_in[1];
    double* ws = (double*)d_ws;
    float* out = (float*)d_out;

    hybrid_init<<<1, 256, 0, stream>>>(ws);
    dim3 grid(W / TX, H / STRIP, NIMG);
    hybrid_main<<<grid, dim3(512), 0, stream>>>(pred, targ, ws);
    hybrid_fin<<<1, 64, 0, stream>>>(ws, out);
}

// Round 9
// 140.078 us; speedup vs baseline: 1.1375x; 1.0140x over previous
//
#include <hip/hip_runtime.h>

// HybridLoss: 0.8*MSE + 0.2*(1-SSIM), SSIM via separable 11x11 Gaussian (sigma=1.5)
// Input: pred, target f32 (32,3,512,512). Output: scalar f32.
// Streaming strip (64 wide x 128 tall), 256-thread blocks, 16-row chunks through a
// 26-row circular LDS float4 plane: (mu_x, mu_y, E[x^2+y^2], E[xy]).
// T14 async-stage: next chunk's global loads issue BEFORE vconv (consumed after
// barrier B) so HBM latency hides under vconv instead of stalling hconv.
// __launch_bounds__ min-waves stays 4: min-waves=6 clamped VGPR to 40 and spilled
// (r5: 80 MB, r7: 59 MB scratch writes). r8: CHUNK=32/512-thread was worse (3
// blocks/CU, 8-wave barrier convoy) -> back to r6's 5 blocks/CU geometry.

#define W 512
#define H 512
#define NIMG 96
#define TX 64
#define CHUNK 16
#define STRIP 128
#define NITER 8            // STRIP/CHUNK
#define BUF 26             // circular rows: CHUNK + 10-row window overlap
#define PAD4 65            // float4 row stride: 1040 B == 16 mod 128 -> uniform banks
#define NSLOT 128

// symmetric gaussian: gw[k] == gwu[k<6 ? k : 10-k], k compile-time in unrolled loops
#define GW(k) gwu[(k) < 6 ? (k) : 10 - (k)]

__global__ void hybrid_init(double* __restrict__ ws) {
    int t = threadIdx.x;
    if (t < 2 * NSLOT) ws[t] = 0.0;
}

__global__ __launch_bounds__(256, 4) void hybrid_main(
    const float* __restrict__ pred, const float* __restrict__ targ,
    double* __restrict__ ws)
{
    __shared__ float4 s_q[BUF][PAD4];   // 26*1040 = 27040 B -> 5 blocks/CU

    const int tid = threadIdx.x;
    const float* __restrict__ pp = pred + (size_t)blockIdx.z * (H * W);
    const float* __restrict__ tp = targ + (size_t)blockIdx.z * (H * W);
    const int xbase = blockIdx.x * TX;
    const int Y0 = blockIdx.y * STRIP;

    // Normalized 1D Gaussian, 6 unique weights (symmetric), f32 like ref
    float gwu[6];
    {
        float s = 0.f;
#pragma unroll
        for (int k = 0; k < 6; ++k) {
            float d = (float)(k - 5);
            gwu[k] = expf(-d * d / 4.5f);   // 2*sigma^2 = 4.5
            s += (k < 5) ? 2.f * gwu[k] : gwu[k];
        }
        float inv = 1.f / s;
#pragma unroll
        for (int k = 0; k < 6; ++k) gwu[k] *= inv;
    }

    const int hrow_i = tid >> 4;       // 0..15 : hconv row-in-chunk
    const int g      = tid & 15;       // 4-col group
    const int c0     = g * 4;
    const int A0     = xbase + c0 - 8; // aligned 20-px window [A0, A0+20)
    const bool inX   = (A0 >= 0) && (A0 + 20 <= W);

    const int wv = tid >> 6;           // wave 0..3 (vconv 4-row runs)
    const int cc = tid & 63;           // output column within tile

    float mse_local = 0.f, ssim_local = 0.f;
    float pxa[20], pya[20];            // persistent prefetch registers (one row)

    // Issue loads for image row gy into pxa/pya (zeros outside image).
    auto load_row = [&](int gy) {
        if (gy >= 0 && gy < H) {
            const float* __restrict__ px = pp + (size_t)gy * W;
            const float* __restrict__ py = tp + (size_t)gy * W;
            if (inX) {
                const float4* qx = (const float4*)(px + A0);
                const float4* qy = (const float4*)(py + A0);
#pragma unroll
                for (int v = 0; v < 5; ++v) {
                    float4 a = qx[v], b = qy[v];
                    pxa[4*v+0]=a.x; pxa[4*v+1]=a.y; pxa[4*v+2]=a.z; pxa[4*v+3]=a.w;
                    pya[4*v+0]=b.x; pya[4*v+1]=b.y; pya[4*v+2]=b.z; pya[4*v+3]=b.w;
                }
            } else {
#pragma unroll
                for (int j = 0; j < 20; ++j) {
                    int col = A0 + j;
                    bool ok = (col >= 0) && (col < W);
                    pxa[j] = ok ? px[col] : 0.f;
                    pya[j] = ok ? py[col] : 0.f;
                }
            }
        } else {
#pragma unroll
            for (int j = 0; j < 20; ++j) { pxa[j] = 0.f; pya[j] = 0.f; }
        }
    };

    // Consume pxa/pya: MSE (raw) + clip + horizontal 11-tap of 4 quantities -> LDS.
    auto hconv_compute = [&](int slot, bool own) {
        if (own) {
#pragma unroll
            for (int c = 0; c < 4; ++c) {
                float d = pxa[8 + c] - pya[8 + c];
                mse_local = fmaf(d, d, mse_local);
            }
        }
        float a0[4]={0,0,0,0}, a1[4]={0,0,0,0}, a2[4]={0,0,0,0}, a3[4]={0,0,0,0};
#pragma unroll
        for (int j = 0; j < 14; ++j) {        // window positions 3..16
            float cx = __builtin_amdgcn_fmed3f(pxa[3 + j], 0.f, 1.f);
            float yv = pya[3 + j];
            float s2 = fmaf(yv, yv, cx * cx); // x^2 + y^2
            float xy = cx * yv;
#pragma unroll
            for (int i = 0; i < 4; ++i) {
                int k = j - i;
                if (k >= 0 && k < 11) {
                    float w = GW(k);
                    a0[i] = fmaf(w, cx, a0[i]);
                    a1[i] = fmaf(w, yv, a1[i]);
                    a2[i] = fmaf(w, s2, a2[i]);
                    a3[i] = fmaf(w, xy, a3[i]);
                }
            }
        }
#pragma unroll
        for (int i = 0; i < 4; ++i)
            s_q[slot][c0 + i] = make_float4(a0[i], a1[i], a2[i], a3[i]);
    };

    // Prologue: ext rows 0..9 (gy = Y0-5..Y0+4) -> slots 0..9; then prefetch k=0.
    if (hrow_i < 10) {
        load_row(Y0 - 5 + hrow_i);
        hconv_compute(hrow_i, hrow_i >= 5);
    }
    load_row(Y0 + 5 + hrow_i);            // ext rows 10..25 for iter 0

    const float C1 = 1e-4f, C2 = 9e-4f;

#pragma unroll
    for (int k = 0; k < NITER; ++k) {
        const int hb = (10 + CHUNK * k) % BUF;  // compile-time
        const int vb = (CHUNK * k) % BUF;       // compile-time

        // ---- hconv from prefetched regs: ext rows 16k+10 .. 16k+25 ----
        {
            int ext  = CHUNK * k + 10 + hrow_i;
            int slot = hb + hrow_i; if (slot >= BUF) slot -= BUF;
            hconv_compute(slot, ext <= STRIP + 4);
        }
        __syncthreads();   // A: hconv writes visible

        // ---- issue next chunk's loads; latency hides under vconv ----
        if (k + 1 < NITER) load_row(Y0 + 5 + CHUNK * (k + 1) + hrow_i);

        // ---- vconv: output rows 16k + 4*wv .. +3 (1 task/thread) ----
        {
            int t0 = vb + 4 * wv; if (t0 >= BUF) t0 -= BUF;
            float ax[4]={0,0,0,0}, ay[4]={0,0,0,0};
            float as[4]={0,0,0,0}, axy[4]={0,0,0,0};
#pragma unroll
            for (int j = 0; j < 14; ++j) {
                int s = t0 + j; if (s >= BUF) s -= BUF;
                float4 q = s_q[s][cc];
#pragma unroll
                for (int i = 0; i < 4; ++i) {
                    int kk = j - i;
                    if (kk >= 0 && kk < 11) {
                        float w = GW(kk);
                        ax [i] = fmaf(w, q.x, ax [i]);
                        ay [i] = fmaf(w, q.y, ay [i]);
                        as [i] = fmaf(w, q.z, as [i]);
                        axy[i] = fmaf(w, q.w, axy[i]);
                    }
                }
            }
#pragma unroll
            for (int i = 0; i < 4; ++i) {
                float mu_x2 = ax[i]*ax[i], mu_y2 = ay[i]*ay[i], mu_xy = ax[i]*ay[i];
                float ssum = as[i] - mu_x2 - mu_y2;      // sigma_x2 + sigma_y2
                float sxy  = axy[i] - mu_xy;
                float num = (2.f*mu_xy + C1) * (2.f*sxy + C2);
                float den = (mu_x2 + mu_y2 + C1) * (ssum + C2);
                ssim_local = fmaf(num, __builtin_amdgcn_rcpf(den), ssim_local);
            }
        }
        __syncthreads();   // B: vconv reads done (also drains prefetch vmcnt)
    }

    // ---- Per-wave reduction + spread f64 atomics ----
    float m = mse_local, s2 = ssim_local;
#pragma unroll
    for (int off = 32; off; off >>= 1) {
        m  += __shfl_down(m, off);
        s2 += __shfl_down(s2, off);
    }
    if ((tid & 63) == 0) {
        int flat = blockIdx.x + 8 * (blockIdx.y + 4 * blockIdx.z);
        int slot = (flat * 4 + wv) & (NSLOT - 1);
        atomicAdd(&ws[slot], (double)m);
        atomicAdd(&ws[NSLOT + slot], (double)s2);
    }
}

__global__ void hybrid_fin(const double* __restrict__ ws, float* __restrict__ out) {
    int t = threadIdx.x;  // 64 threads
    double m = ws[t] + ws[t + 64];
    double s = ws[NSLOT + t] + ws[NSLOT + t + 64];
#pragma unroll
    for (int off = 32; off; off >>= 1) {
        m += __shfl_down(m, off);
        s += __shfl_down(s, off);
    }
    if (t == 0) {
        const double N = (double)NIMG * H * W;
        double mse  = m / N;
        double ssim = s / N;
        out[0] = (float)(0.8 * mse + 0.2 * (1.0 - ssim));
    }
}

extern "C" void kernel_launch(void* const* d_in, const int* in_sizes, int n_in,
                              void* d_out, int out_size, void* d_ws, size_t ws_size,
                              hipStream_t stream) {
    const float* pred = (const float*)d_in[0];
    const float* targ = (const float*)d_in[1];
    double* ws = (double*)d_ws;
    float* out = (float*)d_out;

    hybrid_init<<<1, 256, 0, stream>>>(ws);
    dim3 grid(W / TX, H / STRIP, NIMG);
    hybrid_main<<<grid, dim3(256), 0, stream>>>(pred, targ, ws);
    hybrid_fin<<<1, 64, 0, stream>>>(ws, out);
}